// Round 11
// baseline (1277.489 us; speedup 1.0000x reference)
//
#include <hip/hip_runtime.h>
#include <cfloat>
#include <cstdint>
#include <cstddef>

// Problem constants
#define M_ROWS 16384
#define NE     8192
#define KD     256

// d_out layout (float elements)
#define OFF_LOSS   0ULL
#define OFF_ZQ     1ULL
#define OFF_PERP   4194305ULL
#define OFF_ONEHOT 4194306ULL
#define OFF_I0     138412034ULL
#define OFF_I1     138428418ULL

// Scratch inside the one-hot output region (zeroed AFTER use).
// base = out + OFF_ONEHOT + 2 (16B-aligned). Offsets in floats:
#define SCR_Z16  0ULL         // fp16[16384][256] BK32-swizzled = 8 MB
#define SCR_E16  2097152ULL   // fp16[8192][256] BK32-swizzled (x256 scale) = 4 MB
#define SCR_Z32T 3145728ULL   // fp32[16384][256] row-major transposed z = 16 MB
#define SCR_PART 7340032ULL   // float4[16384][128] = 32 MB

// d_ws layout (4-byte units)
#define WS_I0    0        // int[16384]
#define WS_HIST  16384    // int[8192]
#define WS_ENORM 24576    // float[8192]
#define WS_CNORM 32768    // float[16384]
#define WS_T0SUM 49152    // double (2 float slots, 8B-aligned)
#define WS_TOTAL 49154

// mfma kernel dynamic LDS: Zs 128K + Es 2x8K + enb 8K
#define SMEM_BYTES 155648

typedef _Float16 fp16x8 __attribute__((ext_vector_type(8)));
typedef float    floatx16 __attribute__((ext_vector_type(16)));

// ------------------------------------------------- zero one-hot region (537 MB)
__global__ void zero_onehot_kernel(float* __restrict__ out) {
    size_t tidg = (size_t)blockIdx.x * 1024 + threadIdx.x;   // 4096 x 1024
    float4* base = (float4*)(out + OFF_ONEHOT + 2);
    const float4 zz = make_float4(0.f, 0.f, 0.f, 0.f);
#pragma unroll
    for (int i = 0; i < 8; i++) {
        size_t q = tidg + (size_t)i * 4194304ULL;
        if (q < 33554431ULL) base[q] = zz;
    }
    if (tidg == 0) {
        out[OFF_ONEHOT + 0] = 0.f;
        out[OFF_ONEHOT + 1] = 0.f;
        out[OFF_ONEHOT + 134217726ULL] = 0.f;
        out[OFF_ONEHOT + 134217727ULL] = 0.f;
    }
}

// ---------------------------------------------------------------- scatter ones
__global__ void scatter_ones_kernel(const int* __restrict__ ws_i0, float* __restrict__ out) {
    int r = blockIdx.x * 256 + threadIdx.x;   // 64 x 256
    int j = ws_i0[r] & (NE - 1);
    out[OFF_ONEHOT + (size_t)r * NE + j] = 1.0f;
}

// ------------------------------------------------------------------------
// numpy float32 pairwise sum of squares over 256 elements (R2-validated)
__device__ __forceinline__ float pairwise16_sq(const float* row, int lane16) {
    const int h = lane16 >> 3, j = lane16 & 7;
    const float* p = row + h * 128 + j;
    float x = p[0];
    float r = __fmul_rn(x, x);
#pragma unroll
    for (int i = 1; i < 16; i++) {
        float y = p[i * 8];
        r = __fadd_rn(r, __fmul_rn(y, y));
    }
    float s = __fadd_rn(r, __shfl_xor(r, 1));
    s = __fadd_rn(s, __shfl_xor(s, 2));
    s = __fadd_rn(s, __shfl_xor(s, 4));
    s = __fadd_rn(s, __shfl_xor(s, 8));
    return s;
}

// ---------------------------------------------------------------- e -> e16 + enorm + zero hist
// e16 (16B units): unit = ((code>>7)*8 + kb)*512 + (code&127)*4 + (k8 ^ (code&3)),
// k = kb*32 + k8*8 + e.
__global__ void split_e_kernel(const float* __restrict__ emb, _Float16* __restrict__ e16,
                               float* __restrict__ enorm, int* __restrict__ hist,
                               float* __restrict__ wsf) {
    __shared__ float ef[16][261];
    const int tid = threadIdx.x;          // 256
    const int row0 = blockIdx.x * 16;     // 512 blocks
#pragma unroll
    for (int p = 0; p < 4; p++) {
        int q = p * 256 + tid;
        int rl = q >> 6, kq = q & 63;
        float4 v = *(const float4*)(emb + (size_t)(row0 + rl) * KD + kq * 4);
        ef[rl][kq * 4 + 0] = v.x; ef[rl][kq * 4 + 1] = v.y;
        ef[rl][kq * 4 + 2] = v.z; ef[rl][kq * 4 + 3] = v.w;
    }
    __syncthreads();
#pragma unroll
    for (int p = 0; p < 2; p++) {
        int u = p * 256 + tid;            // 512 units: 16 codes x 32 octets
        int rl = u >> 5, k8g = u & 31;
        int code = row0 + rl;
        fp16x8 vh;
#pragma unroll
        for (int e = 0; e < 8; e++) vh[e] = (_Float16)(ef[rl][k8g * 8 + e] * 256.0f);
        int kb = k8g >> 2, k8 = k8g & 3;
        size_t unit = ((size_t)(code >> 7) * 8 + kb) * 512 + (size_t)(code & 127) * 4 + (k8 ^ (code & 3));
        *(fp16x8*)(e16 + unit * 8) = vh;
    }
    {
        int rl = tid >> 4, lane16 = tid & 15;
        float s = pairwise16_sq(&ef[rl][0], lane16);
        if (lane16 == 0) enorm[row0 + rl] = s;
    }
    if (blockIdx.x < 32) hist[blockIdx.x * 256 + tid] = 0;
    if (blockIdx.x == 32 && tid < 2) wsf[WS_T0SUM + tid] = 0.0f;
}

// ---------------------------------------------------------------- z -> z16 + z32t + cnorm
__global__ void split_z_kernel(const float* __restrict__ z, _Float16* __restrict__ z16,
                               float* __restrict__ z32t, float* __restrict__ cnorm) {
    __shared__ float zf[64][261];
    const int tid = threadIdx.x;            // 256
    const int r0  = blockIdx.x * 64;        // 256 row-blocks
    const int b   = r0 >> 10;
    const int hw0 = r0 & 1023;
    const float* zb = z + ((size_t)b << 18) + hw0;
#pragma unroll
    for (int p = 0; p < 16; p++) {
        int q = p * 256 + tid;              // 4096 quads: 256 c x 16 hw-quads
        int c = q >> 4, hq = q & 15;
        float4 v = *(const float4*)(zb + ((size_t)c << 10) + hq * 4);
        zf[hq * 4 + 0][c] = v.x; zf[hq * 4 + 1][c] = v.y;
        zf[hq * 4 + 2][c] = v.z; zf[hq * 4 + 3][c] = v.w;
    }
    __syncthreads();
#pragma unroll
    for (int rr = 0; rr < 4; rr++) {
        int row = rr * 16 + (tid >> 4);
        float s = pairwise16_sq(&zf[row][0], tid & 15);
        if ((tid & 15) == 0) cnorm[r0 + row] = s;
    }
#pragma unroll
    for (int p = 0; p < 8; p++) {
        int u = p * 256 + tid;              // 2048 units: 64 rows x 32 octets
        int row = u >> 5, k8g = u & 31;
        int r = r0 + row;
        fp16x8 vh;
#pragma unroll
        for (int e = 0; e < 8; e++) vh[e] = (_Float16)zf[row][k8g * 8 + e];
        int kb = k8g >> 2, k8 = k8g & 3;
        size_t unit = ((size_t)(r >> 7) * 8 + kb) * 512 + (size_t)(r & 127) * 4 + (k8 ^ (r & 3));
        *(fp16x8*)(z16 + unit * 8) = vh;
    }
#pragma unroll
    for (int p = 0; p < 16; p++) {
        int q = p * 256 + tid;              // 4096 quads: 64 rows x 64
        int row = q >> 6, co = (q & 63) * 4;
        float4 v = make_float4(zf[row][co], zf[row][co + 1], zf[row][co + 2], zf[row][co + 3]);
        *(float4*)(z32t + (size_t)(r0 + row) * 256 + co) = v;
    }
}

// ---------------------------------------------------------------- helpers
__device__ __forceinline__ fp16x8 efrag_ld(const _Float16* lds, int rc, int ku) {
    int slot = rc * 4 + (ku ^ (rc & 3));
    return *(const fp16x8*)(lds + slot * 8);
}
__device__ __forceinline__ fp16x8 zfrag_ld(const _Float16* Zs, int kb, int rloc, int ku) {
    int sec = (rloc >> 7) * 8 + kb;
    int slot = sec * 512 + (rloc & 127) * 4 + (ku ^ (rloc & 3));
    return *(const fp16x8*)(Zs + slot * 8);
}

#define MFMA(d, a, b) d = __builtin_amdgcn_mfma_f32_32x32x16_f16(a, b, d, 0, 0, 0)

__device__ __forceinline__ void ins2(float t, int i, float& t0, int& i0, float& t1, int& i1) {
    if (t < t0 || (t == t0 && i < i0)) { t1 = t0; i1 = i0; t0 = t; i0 = i; }
    else if (t < t1 || (t == t1 && i < i1)) { t1 = t; i1 = i; }
}

// ---------------------------------------------------------------- MFMA top-2, z-panel resident
// Block = (cg, nt): 2048-code e-group vs 256-row z-panel (128 KB LDS, loaded once);
// e streamed through 2x8 KB dbuf + 4-deep register queue. Filter granularity:
// top-2 per (jt, wave_m) = 64-code group -> 128 groups/row (more redundant than
// the R8/R9-validated 128-code groups; fixes R10's Output-5 displacement).
__launch_bounds__(512, 2)
__global__ void mfma_top2_kernel(const _Float16* __restrict__ e16, const _Float16* __restrict__ z16,
                                 const float* __restrict__ enorm_g, const float* __restrict__ cnorm_g,
                                 float4* __restrict__ part) {
    extern __shared__ char smem[];
    _Float16* Zs  = (_Float16*)smem;                 // 128 KB: 16 sec x 512 units
    _Float16* Es0 = (_Float16*)(smem + 131072);      // 8 KB
    _Float16* Es1 = (_Float16*)(smem + 139264);      // 8 KB
    float*    enb = (float*)(smem + 147456);         // 2048 floats

    const int tid = threadIdx.x;
    const int lane = tid & 63, wid = tid >> 6;
    const int l31 = lane & 31, half = lane >> 5;
    const int wave_m = wid & 1, wave_n = wid >> 1;   // wn 0..3
    const int cg = blockIdx.x;        // 0..3 (2048 codes)
    const int nt = blockIdx.y;        // 0..63 (256 zrows)
    const int r0 = nt * 256;

    // ---- prologue: z panel (8192 float4), e-norms, e-queue
    const float4* Zg = (const float4*)(z16 + (size_t)nt * 8192 * 8);
    float4* Zl = (float4*)Zs;
#pragma unroll
    for (int p = 0; p < 16; p++) Zl[p * 512 + tid] = Zg[p * 512 + tid];
#pragma unroll
    for (int p = 0; p < 4; p++) enb[p * 512 + tid] = enorm_g[cg * 2048 + p * 512 + tid];

    float Cn[2];
    Cn[0] = cnorm_g[r0 + wave_n * 64 + l31];
    Cn[1] = cnorm_g[r0 + wave_n * 64 + 32 + l31];

    const int rcA0 = wave_m * 64 + l31, rcA1 = rcA0 + 32;
    const int rcB0 = wave_n * 64 + l31, rcB1 = rcB0 + 32;

    const float4* Eg = (const float4*)(e16 + (size_t)cg * 65536 * 8);
    float4 q[4];
#pragma unroll
    for (int d = 0; d < 4; d++) q[d] = Eg[(size_t)d * 512 + tid];
    ((float4*)Es0)[tid] = q[0];   // iter 0
    __syncthreads();

    for (int jt = 0; jt < 16; jt++) {
        floatx16 acc00 = (floatx16)0.f, acc01 = (floatx16)0.f,
                 acc10 = (floatx16)0.f, acc11 = (floatx16)0.f;
#pragma unroll
        for (int kb = 0; kb < 8; kb++) {
            const int it = jt * 8 + kb;
            if (it + 4 < 128) q[kb & 3] = Eg[(size_t)(it + 4) * 512 + tid];   // 4-deep queue
            if (it < 127) {
                float4* dst = (float4*)((it & 1) ? Es0 : Es1);  // buf (it+1)&1
                dst[tid] = q[(kb + 1) & 3];                     // loaded 3 iters ago
            }
            const _Float16* Ecur = (it & 1) ? Es1 : Es0;
#pragma unroll
            for (int ks = 0; ks < 2; ks++) {
                const int ku = ks * 2 + half;
                fp16x8 a0 = efrag_ld(Ecur, rcA0, ku);
                fp16x8 a1 = efrag_ld(Ecur, rcA1, ku);
                fp16x8 b0 = zfrag_ld(Zs, kb, rcB0, ku);
                fp16x8 b1 = zfrag_ld(Zs, kb, rcB1, ku);
                MFMA(acc00, a0, b0); MFMA(acc01, a0, b1);
                MFMA(acc10, a1, b0); MFMA(acc11, a1, b1);
            }
            __syncthreads();
        }
        // per-jt fold + in-wave merge + part write (no barriers needed)
        float t0s[2] = {FLT_MAX, FLT_MAX}, t1s[2] = {FLT_MAX, FLT_MAX};
        int   i0s[2] = {0x7fffffff, 0x7fffffff}, i1s[2] = {0x7fffffff, 0x7fffffff};
        // C/D 32x32: col = lane&31 (zrow), row = (reg&3)+8*(reg>>2)+4*half (code)
#pragma unroll
        for (int mt = 0; mt < 2; mt++) {
#pragma unroll
            for (int reg = 0; reg < 16; reg++) {
                const int rl = (reg & 3) + 8 * (reg >> 2) + 4 * half;
                const int cloc = wave_m * 64 + mt * 32 + rl;
                const int code = cg * 2048 + jt * 128 + cloc;
                const float E = enb[jt * 128 + cloc];
                float g0 = (mt == 0) ? acc00[reg] : acc10[reg];
                float g1 = (mt == 0) ? acc01[reg] : acc11[reg];
                ins2(fmaf(-0.0078125f, g0, Cn[0] + E), code, t0s[0], i0s[0], t1s[0], i1s[0]);
                ins2(fmaf(-0.0078125f, g1, Cn[1] + E), code, t0s[1], i0s[1], t1s[1], i1s[1]);
            }
        }
        // xor-32 merge: both halves cover complementary code-subsets of this wave's 64
#pragma unroll
        for (int s = 0; s < 2; s++) {
            float o0 = __shfl_xor(t0s[s], 32), o1 = __shfl_xor(t1s[s], 32);
            int  oi0 = __shfl_xor(i0s[s], 32), oi1 = __shfl_xor(i1s[s], 32);
            ins2(o0, oi0, t0s[s], i0s[s], t1s[s], i1s[s]);
            ins2(o1, oi1, t0s[s], i0s[s], t1s[s], i1s[s]);
        }
        if (lane < 32) {
            const int grp = cg * 32 + jt * 2 + wave_m;   // 0..127
#pragma unroll
            for (int s = 0; s < 2; s++) {
                int zr = wave_n * 64 + s * 32 + l31;
                float4 o;
                o.x = t0s[s]; o.y = t1s[s];
                o.z = __int_as_float(i0s[s]); o.w = __int_as_float(i1s[s]);
                part[(size_t)(r0 + zr) * 128 + grp] = o;
            }
        }
    }
}

// ---------------------------------------------------------------- fp64 rescore, lane-parallel
// 128 groups x top-2 = 256 candidates; each lane owns 2 part entries (coalesced).
__global__ void rescore_kernel(const float* __restrict__ z32t, const float* __restrict__ emb,
                               const float* __restrict__ enorm_g, const float* __restrict__ cnorm_g,
                               const float4* __restrict__ part, float* __restrict__ out,
                               int* __restrict__ ws_i0, int* __restrict__ hist,
                               double* __restrict__ t0sum) {
    const int tid  = threadIdx.x;
    const int lane = tid & 63, wid = tid >> 6;
    const int r = blockIdx.x * 4 + wid;       // 4096 blocks x 4 waves

    float4 pa = part[(size_t)r * 128 + lane];
    float4 pb = part[(size_t)r * 128 + 64 + lane];
    float v0 = pa.x, v1 = pa.y, v2 = pb.x, v3 = pb.y;
    int   j0 = __float_as_int(pa.z), j1 = __float_as_int(pa.w);
    int   j2 = __float_as_int(pb.z), j3 = __float_as_int(pb.w);

    // per-lane two smallest of 4, then butterfly across 64 lanes
    float m1 = fminf(v0, v1), M1 = fmaxf(v0, v1);
    float n1 = fminf(v2, v3), N1 = fmaxf(v2, v3);
    float a = fminf(m1, n1);
    float bmx = fminf(fmaxf(m1, n1), fminf(M1, N1));
#pragma unroll
    for (int m = 1; m < 64; m <<= 1) {
        float oa = __shfl_xor(a, m), ob = __shfl_xor(bmx, m);
        float na = fminf(a, oa);
        bmx = fminf(fmaxf(a, oa), fminf(bmx, ob));
        a = na;
    }
    const float T = bmx + 1.2e-4f;   // R5-validated slack
    const float C = cnorm_g[r];

    const int c4 = lane * 4;
    float4 zv = *(const float4*)(z32t + (size_t)r * 256 + c4);
    const double zv0 = (double)zv.x, zv1 = (double)zv.y, zv2 = (double)zv.z, zv3 = (double)zv.w;

    float bt0 = FLT_MAX, bt1 = FLT_MAX;
    int   bi0 = NE - 1, bi1 = NE - 1;
    unsigned long long msk[4];
    msk[0] = __ballot(v0 <= T);
    msk[1] = __ballot(v1 <= T);
    msk[2] = __ballot(v2 <= T);
    msk[3] = __ballot(v3 <= T);
    const int jsel[4] = {j0, j1, j2, j3};
    for (int pass = 0; pass < 4; pass++) {
        unsigned long long mm = msk[pass];
        while (mm) {
            int g = __builtin_ctzll(mm);
            mm &= mm - 1;
            int j = __shfl(jsel[pass], g) & (NE - 1);
            float4 ev = *(const float4*)(emb + ((size_t)j << 8) + c4);
            double gl = zv0 * (double)ev.x + zv1 * (double)ev.y +
                        zv2 * (double)ev.z + zv3 * (double)ev.w;
#pragma unroll
            for (int m = 1; m < 64; m <<= 1) gl += __shfl_xor(gl, m);
            float g2 = (float)(2.0 * gl);
            float tex = (C + enorm_g[j]) - g2;
            if (tex < bt0 || (tex == bt0 && j < bi0)) {
                bt1 = bt0; bi1 = bi0; bt0 = tex; bi0 = j;
            } else if (tex < bt1 || (tex == bt1 && j < bi1)) {
                bt1 = tex; bi1 = j;
            }
        }
    }

    if (lane == 0) {
        out[OFF_I0 + r] = (float)bi0;
        out[OFF_I1 + r] = (float)bi1;
        ws_i0[r] = bi0;
        atomicAdd(&hist[bi0], 1);
    }
    __shared__ double red[4];
    if (lane == 0) red[wid] = (double)bt0;
    __syncthreads();
    if (tid == 0) atomicAdd(t0sum, (red[0] + red[1]) + (red[2] + red[3]));
}

// ---------------------------------------------------------------- z_q gather (LDS transpose)
__global__ void zq_kernel(const float* __restrict__ emb, const int* __restrict__ ws_i0,
                          float* __restrict__ out) {
    __shared__ float zt[64][65];
    const int tid = threadIdx.x;          // 256
    const int r0  = blockIdx.x * 64;      // 256 blocks
    const int b   = r0 >> 10;
    const int hw0 = r0 & 1023;
    const int kb  = blockIdx.y;           // 4 chunks of 64 channels
#pragma unroll
    for (int p = 0; p < 4; p++) {
        int q = p * 256 + tid;            // 1024 quads: 64 rows x 16
        int row = q >> 4, co = (q & 15) * 4;
        int idx = ws_i0[r0 + row] & (NE - 1);
        float4 v = *(const float4*)(emb + ((size_t)idx << 8) + kb * 64 + co);
        zt[row][co + 0] = v.x; zt[row][co + 1] = v.y;
        zt[row][co + 2] = v.z; zt[row][co + 3] = v.w;
    }
    __syncthreads();
#pragma unroll
    for (int p = 0; p < 4; p++) {
        int q = p * 256 + tid;            // 1024: 64 c x 16 hw-quads
        int c = q >> 4, h4 = (q & 15) * 4;
        float4 v = make_float4(zt[h4 + 0][c], zt[h4 + 1][c], zt[h4 + 2][c], zt[h4 + 3][c]);
        *(float4*)(out + OFF_ZQ + (((size_t)b * 256 + kb * 64 + c) << 10) + hw0 + h4) = v;
    }
}

// ---------------------------------------------------------------- finalize
__global__ void finalize_kernel(const int* __restrict__ hist, const double* __restrict__ t0sum,
                                float* __restrict__ out) {
    __shared__ float red[256];
    float s = 0.f;
    for (int j = threadIdx.x; j < NE; j += 256) {
        float p = (float)hist[j] * (1.0f / 16384.0f);
        s += p * logf(p + 1e-10f);
    }
    red[threadIdx.x] = s;
    __syncthreads();
    for (int m = 128; m; m >>= 1) {
        if (threadIdx.x < m) red[threadIdx.x] += red[threadIdx.x + m];
        __syncthreads();
    }
    if (threadIdx.x == 0) {
        out[OFF_PERP] = expf(-red[0]);
        out[OFF_LOSS] = 1.25f * (float)(t0sum[0] * (1.0 / 4194304.0));
    }
}

extern "C" void kernel_launch(void* const* d_in, const int* in_sizes, int n_in,
                              void* d_out, int out_size, void* d_ws, size_t ws_size,
                              hipStream_t stream) {
    const float* z   = (const float*)d_in[0];
    const float* emb = (const float*)d_in[1];
    float* out = (float*)d_out;
    float* ws  = (float*)d_ws;

    int*    ws_i0    = (int*)ws + WS_I0;
    int*    ws_hist  = (int*)ws + WS_HIST;
    float*  ws_enorm = ws + WS_ENORM;
    float*  ws_cnorm = ws + WS_CNORM;
    double* ws_t0sum = (double*)(ws + WS_T0SUM);

    float* scr = out + OFF_ONEHOT + 2;   // 16B-aligned scratch in one-hot region
    _Float16* z16 = (_Float16*)(scr + SCR_Z16);
    _Float16* e16 = (_Float16*)(scr + SCR_E16);
    float*  z32t  = scr + SCR_Z32T;
    float4* part  = (float4*)(scr + SCR_PART);

    static bool attr_set = false;
    if (!attr_set) {
        hipFuncSetAttribute((const void*)mfma_top2_kernel,
                            hipFuncAttributeMaxDynamicSharedMemorySize, SMEM_BYTES);
        attr_set = true;
    }

    hipLaunchKernelGGL(split_e_kernel, dim3(512), dim3(256), 0, stream,
                       emb, e16, ws_enorm, ws_hist, ws);
    hipLaunchKernelGGL(split_z_kernel, dim3(256), dim3(256), 0, stream,
                       z, z16, z32t, ws_cnorm);
    hipLaunchKernelGGL(mfma_top2_kernel, dim3(4, 64), dim3(512), SMEM_BYTES, stream,
                       e16, z16, ws_enorm, ws_cnorm, part);
    hipLaunchKernelGGL(rescore_kernel, dim3(4096), dim3(256), 0, stream,
                       z32t, emb, ws_enorm, ws_cnorm, part, out, ws_i0, ws_hist, ws_t0sum);
    hipLaunchKernelGGL(zero_onehot_kernel, dim3(4096), dim3(1024), 0, stream, out);
    hipLaunchKernelGGL(scatter_ones_kernel, dim3(64), dim3(256), 0, stream, ws_i0, out);
    hipLaunchKernelGGL(zq_kernel, dim3(256, 4), dim3(256), 0, stream, emb, ws_i0, out);
    hipLaunchKernelGGL(finalize_kernel, dim3(1), dim3(256), 0, stream,
                       ws_hist, ws_t0sum, out);
}